// Round 4
// baseline (1592.331 us; speedup 1.0000x reference)
//
#include <hip/hip_runtime.h>
#include <math.h>

#define N 1024
#define SLOTS 16   // rows per lane: row r owned by lane (r & 63), slot (r >> 6)
#define K 8        // precomputed candidates per row

// (v2,f2) beats (v1,f1): larger value wins; tie -> smaller flat index
__device__ __forceinline__ bool better(float v2, int f2, float v1, int f1) {
    return (v2 > v1) || (v2 == v1 && f2 < f1);
}

// One reduce level via DPP (VALU latency, no DS pipe).
template<int CTRL>
__device__ __forceinline__ void dpp_step(float& v, int& f) {
    int ovi = __builtin_amdgcn_update_dpp(0, __float_as_int(v), CTRL, 0xF, 0xF, true);
    int ofi = __builtin_amdgcn_update_dpp(0, f, CTRL, 0xF, 0xF, true);
    float ov = __int_as_float(ovi);
    if (better(ov, ofi, v, f)) { v = ov; f = ofi; }
}

// Full-wave argmax on (v,f); result broadcast to all lanes.
__device__ __forceinline__ void wave_argmax(float& v, int& f) {
    dpp_step<0xB1>(v, f);    // quad_perm xor1
    dpp_step<0x4E>(v, f);    // quad_perm xor2
    dpp_step<0x141>(v, f);   // row_half_mirror (xor within 8)
    dpp_step<0x140>(v, f);   // row_mirror      (xor within 16)
    float v0 = __int_as_float(__builtin_amdgcn_readlane(__float_as_int(v), 0));
    int   f0 = __builtin_amdgcn_readlane(f, 0);
    float v1 = __int_as_float(__builtin_amdgcn_readlane(__float_as_int(v), 16));
    int   f1 = __builtin_amdgcn_readlane(f, 16);
    float v2 = __int_as_float(__builtin_amdgcn_readlane(__float_as_int(v), 32));
    int   f2 = __builtin_amdgcn_readlane(f, 32);
    float v3 = __int_as_float(__builtin_amdgcn_readlane(__float_as_int(v), 48));
    int   f3 = __builtin_amdgcn_readlane(f, 48);
    if (better(v1, f1, v0, f0)) { v0 = v1; f0 = f1; }
    if (better(v3, f3, v2, f2)) { v2 = v3; f2 = f3; }
    if (better(v2, f2, v0, f0)) { v0 = v2; f0 = f2; }
    v = v0; f = f0;
}

// ---------------------------------------------------------------------------
// Kernel 1: exact top-K per row by repeated argmax-with-exclusion.
// Entry: .x = col, .y = float bits of value. Order = (val desc, col asc).
// ---------------------------------------------------------------------------
__global__ __launch_bounds__(256) void init_topk(const float* __restrict__ C,
                                                 uint2* __restrict__ wsList) {
    int row  = (blockIdx.x * blockDim.x + threadIdx.x) >> 6;
    int lane = threadIdx.x & 63;
    if (row >= N) return;
    const float* rp = C + (size_t)row * N;
    float rv[SLOTS];
    #pragma unroll
    for (int k = 0; k < SLOTS; ++k) rv[k] = rp[(k << 6) + lane];
    unsigned excl = 0;
    for (int pass = 0; pass < K; ++pass) {
        float best = -INFINITY; int bc = N;
        #pragma unroll
        for (int k = 0; k < SLOTS; ++k) {
            int c = (k << 6) + lane;
            bool ex = (excl >> k) & 1u;
            if (!ex && rv[k] > best) { best = rv[k]; bc = c; }
        }
        wave_argmax(best, bc);
        if (lane == (bc & 63)) excl |= 1u << (bc >> 6);
        if (lane == 0) wsList[row * K + pass] = make_uint2((unsigned)bc, __float_as_uint(best));
    }
}

// ---------------------------------------------------------------------------
// Kernel 2: 1024 sequential greedy steps in ONE wave.
// Row cache in REGISTERS (val[s], col[s]); per-lane local best (lbV,lbF)
// maintained incrementally. Pops are wave-cooperative: lanes 0-7 probe all
// K list entries of one row in a single LDS round-trip.
// ---------------------------------------------------------------------------
__global__ __launch_bounds__(64) void greedy_wave(const float* __restrict__ C,
                                                  const uint2* __restrict__ wsList,
                                                  int* __restrict__ out,
                                                  int haveList) {
    __shared__ __align__(16) uint2 list[N * K];   // 64 KB
    __shared__ unsigned colUsed[N / 32];

    const int lane = threadIdx.x;
    float val[SLOTS];
    int   col[SLOTS];
    unsigned maskbits = 0;            // bit k: col (k*64+lane) used (for rescans)

    if (lane < N / 32) colUsed[lane] = 0u;

    if (haveList) {
        const uint4* src = (const uint4*)wsList;
        uint4* dst = (uint4*)list;
        #pragma unroll 8
        for (int it = 0; it < (N * K) / (2 * 64); ++it)   // 64 KB copy-in
            dst[it * 64 + lane] = src[it * 64 + lane];
        #pragma unroll
        for (int s = 0; s < SLOTS; ++s) {
            uint2 e = list[((s << 6) + lane) * K];        // entry 0 per owned row
            val[s] = __uint_as_float(e.y);
            col[s] = (int)e.x;
        }
    } else {
        // fallback (tiny ws): cooperative full scan per row
        #pragma unroll 1
        for (int r = 0; r < N; ++r) {
            const float* rp = C + (size_t)r * N;
            float best = -INFINITY; int bcc = N - 1;
            #pragma unroll
            for (int k = 0; k < SLOTS; ++k) {
                int c = (k << 6) + lane;
                float vv = rp[c];
                if (vv > best) { best = vv; bcc = c; }
            }
            wave_argmax(best, bcc);
            if (lane == (r & 63)) {
                const int s0 = r >> 6;
                #pragma unroll
                for (int ss = 0; ss < SLOTS; ++ss)
                    if (ss == s0) { val[ss] = best; col[ss] = bcc; }
            }
        }
    }
    __syncthreads();

    float lbV; int lbF;
    auto recomputeLB = [&]() {
        float tv[SLOTS]; int tf_[SLOTS];
        #pragma unroll
        for (int s = 0; s < SLOTS; ++s) {
            tv[s]  = val[s];
            tf_[s] = (s << 16) | (lane << 10) | (col[s] & (N - 1));  // r<<10 | c
        }
        #pragma unroll
        for (int st = 1; st < SLOTS; st <<= 1) {
            #pragma unroll
            for (int s = 0; s < SLOTS; s += (st << 1)) {
                if (better(tv[s + st], tf_[s + st], tv[s], tf_[s])) {
                    tv[s] = tv[s + st]; tf_[s] = tf_[s + st];
                }
            }
        }
        lbV = tv[0]; lbF = tf_[0];
    };
    recomputeLB();

    #pragma unroll 1
    for (int iter = 0; iter < N; ++iter) {
        // ---- global argmax over 64 per-lane local bests --------------------
        float v = lbV; int f = lbF;
        wave_argmax(v, f);
        const int br = f >> 10;
        const int bc = f & (N - 1);

        bool needLB = false;

        // ---- retire winner row (owner lane) --------------------------------
        if (lane == (br & 63)) {
            const int s0 = br >> 6;
            #pragma unroll
            for (int ss = 0; ss < SLOTS; ++ss)
                if (ss == s0) { val[ss] = -INFINITY; col[ss] = -2; }
            needLB = true;
            out[N + br] = bc;
        }
        // ---- mark column used ---------------------------------------------
        if (lane == (bc & 63)) maskbits |= 1u << (bc >> 6);
        if (lane == 0) colUsed[bc >> 5] |= 1u << (bc & 31);

        // ---- rows whose cached best column just died -----------------------
        unsigned pend = 0;
        #pragma unroll
        for (int s = 0; s < SLOTS; ++s)
            if (col[s] == bc) pend |= 1u << s;

        // ---- wave-cooperative pops (typically 0-2 per iteration) -----------
        while (true) {
            unsigned long long pm = __ballot(pend != 0);
            if (!pm) break;
            const int srclane = __ffsll(pm) - 1;
            const unsigned pbits = (unsigned)__builtin_amdgcn_readlane((int)pend, srclane);
            const int s = __ffs(pbits) - 1;
            if (lane == srclane) pend &= pend - 1u;
            const int r = (s << 6) + srclane;

            int foundCol = -1; unsigned foundVB = 0;
            if (haveList) {
                // lanes replicate entries 0..7; two parallel dependent LDS reads
                uint2 e = list[r * K + (lane & 7)];
                bool unused = !((colUsed[e.x >> 5] >> (e.x & 31)) & 1u);
                unsigned long long avail = __ballot(unused) & 0xFFull;
                if (avail) {
                    const int j = (int)(__ffsll(avail) - 1);
                    foundCol = __builtin_amdgcn_readlane((int)e.x, j);
                    foundVB  = (unsigned)__builtin_amdgcn_readlane((int)e.y, j);
                }
            }
            if (foundCol >= 0) {
                if (lane == srclane) {
                    #pragma unroll
                    for (int ss = 0; ss < SLOTS; ++ss)
                        if (ss == s) { val[ss] = __uint_as_float(foundVB); col[ss] = foundCol; }
                    needLB = true;
                }
            } else {
                // list exhausted: cooperative full rescan of row r
                const float* rp = C + (size_t)r * N;
                float best = -INFINITY; int bcc = N - 1;
                #pragma unroll
                for (int k = 0; k < SLOTS; ++k) {
                    int c = (k << 6) + lane;
                    float vv = rp[c];
                    bool used = (maskbits >> k) & 1u;
                    if (!used && vv > best) { best = vv; bcc = c; }
                }
                wave_argmax(best, bcc);
                if (lane == srclane) {
                    #pragma unroll
                    for (int ss = 0; ss < SLOTS; ++ss)
                        if (ss == s) { val[ss] = best; col[ss] = bcc; }
                    needLB = true;
                }
            }
        }

        // ---- only changed lanes redo their 16-wide register tree -----------
        if (needLB) recomputeLB();
    }

    // ---- row-index half of the output: identity ---------------------------
    #pragma unroll
    for (int s = 0; s < SLOTS; ++s) out[(s << 6) + lane] = (s << 6) + lane;
}

// ---------------------------------------------------------------------------
extern "C" void kernel_launch(void* const* d_in, const int* in_sizes, int n_in,
                              void* d_out, int out_size, void* d_ws, size_t ws_size,
                              hipStream_t stream) {
    const float* C = (const float*)d_in[0];
    int* out = (int*)d_out;

    if (ws_size >= (size_t)(N * K * sizeof(uint2))) {
        uint2* lists = (uint2*)d_ws;
        init_topk<<<256, 256, 0, stream>>>(C, lists);
        greedy_wave<<<1, 64, 0, stream>>>(C, lists, out, 1);
    } else {
        greedy_wave<<<1, 64, 0, stream>>>(C, nullptr, out, 0);
    }
}

// Round 5
// 291.215 us; speedup vs baseline: 5.4679x; 5.4679x over previous
//
#include <hip/hip_runtime.h>
#include <math.h>

#define N 1024

// (v2,f2) beats (v1,f1): larger value wins; tie -> smaller flat index
__device__ __forceinline__ bool better(float v2, int f2, float v1, int f1) {
    return (v2 > v1) || (v2 == v1 && f2 < f1);
}

// orderable uint from float bits: larger float -> larger uint (no NaN present)
__device__ __forceinline__ unsigned ordf(unsigned u) {
    return u ^ (unsigned)(((int)u >> 31) | (int)0x80000000);
}

// One reduce level via DPP (VALU latency, no DS pipe).
template<int CTRL>
__device__ __forceinline__ void dpp_step(float& v, int& f) {
    int ovi = __builtin_amdgcn_update_dpp(0, __float_as_int(v), CTRL, 0xF, 0xF, true);
    int ofi = __builtin_amdgcn_update_dpp(0, f, CTRL, 0xF, 0xF, true);
    float ov = __int_as_float(ovi);
    if (better(ov, ofi, v, f)) { v = ov; f = ofi; }
}

// Full-wave argmax on (v,f); result broadcast to all lanes.
__device__ __forceinline__ void wave_argmax(float& v, int& f) {
    dpp_step<0xB1>(v, f);    // quad_perm xor1
    dpp_step<0x4E>(v, f);    // quad_perm xor2
    dpp_step<0x141>(v, f);   // row_half_mirror (xor within 8)
    dpp_step<0x140>(v, f);   // row_mirror      (xor within 16)
    float v0 = __int_as_float(__builtin_amdgcn_readlane(__float_as_int(v), 0));
    int   f0 = __builtin_amdgcn_readlane(f, 0);
    float v1 = __int_as_float(__builtin_amdgcn_readlane(__float_as_int(v), 16));
    int   f1 = __builtin_amdgcn_readlane(f, 16);
    float v2 = __int_as_float(__builtin_amdgcn_readlane(__float_as_int(v), 32));
    int   f2 = __builtin_amdgcn_readlane(f, 32);
    float v3 = __int_as_float(__builtin_amdgcn_readlane(__float_as_int(v), 48));
    int   f3 = __builtin_amdgcn_readlane(f, 48);
    if (better(v1, f1, v0, f0)) { v0 = v1; f0 = f1; }
    if (better(v3, f3, v2, f2)) { v2 = v3; f2 = f3; }
    if (better(v2, f2, v0, f0)) { v0 = v2; f0 = f2; }
    v = v0; f = f0;
}

// ---------------------------------------------------------------------------
// Kernel 1 (grid-wide): round-1 row argmax + column keys.
// Block b owns rows [b*16, b*16+16). Wave w covers cols [w*64, w*64+64),
// lane l -> col w*64+l (coalesced 256B row-chunks). Column max merged via
// global atomicMax on key = (ordf(val)<<32) | (1023-row)  -- deterministic.
// ---------------------------------------------------------------------------
__global__ __launch_bounds__(1024) void init_round1(const float* __restrict__ C,
                                                    unsigned long long* __restrict__ colKeyG,
                                                    unsigned* __restrict__ rowBestColG) {
    __shared__ float rpV[16][16];
    __shared__ int   rpC[16][16];
    const int lane = threadIdx.x & 63;
    const int wave = threadIdx.x >> 6;
    const int r0 = blockIdx.x << 4;
    const int myCol = (wave << 6) + lane;

    float v[16];
    #pragma unroll
    for (int i = 0; i < 16; ++i)
        v[i] = C[(size_t)(r0 + i) * N + myCol];

    // column running max over the block's 16 rows (ascending i: strict > keeps smaller row)
    unsigned bHi = 0u; unsigned bRow = 0u;
    #pragma unroll
    for (int i = 0; i < 16; ++i) {
        unsigned ou = ordf(__float_as_uint(v[i]));
        if (ou > bHi) { bHi = ou; bRow = (unsigned)(r0 + i); }
    }
    atomicMax(&colKeyG[myCol],
              ((unsigned long long)bHi << 32) | (unsigned long long)(N - 1 - bRow));

    // per-row stripe argmax -> LDS, then 16 threads reduce 16 stripes each
    #pragma unroll
    for (int i = 0; i < 16; ++i) {
        float bv = v[i]; int bc = myCol;
        wave_argmax(bv, bc);
        if (lane == 0) { rpV[i][wave] = bv; rpC[i][wave] = bc; }
    }
    __syncthreads();
    if (threadIdx.x < 16) {
        const int i = threadIdx.x;
        float bv = rpV[i][0]; int bc = rpC[i][0];
        #pragma unroll
        for (int w = 1; w < 16; ++w)
            if (better(rpV[i][w], rpC[i][w], bv, bc)) { bv = rpV[i][w]; bc = rpC[i][w]; }
        rowBestColG[r0 + i] = (unsigned)bc;
    }
}

// ---------------------------------------------------------------------------
// Kernel 2: parallel-greedy rounds in ONE 1024-thread workgroup.
// Round: [reset colKey] -> [scan alive rows: row-best + col-key partials]
//        -> [match mutual-best pairs] ; ~3 barriers/round, ~12-18 rounds.
// Identical matching to sequential greedy (locally-dominant-pair theorem).
// ---------------------------------------------------------------------------
__global__ __launch_bounds__(1024) void rounds_kernel(const float* __restrict__ C,
                                                      const unsigned long long* __restrict__ colKeyG,
                                                      const unsigned* __restrict__ rowBestColG,
                                                      int* __restrict__ out,
                                                      int haveInit) {
    __shared__ unsigned long long ck[N];     // column key this round
    __shared__ unsigned rbc[N];              // row best col this round
    __shared__ unsigned rowAliveW[N / 32];
    __shared__ unsigned colUsedW[N / 32];
    __shared__ int nA;

    const int tid = threadIdx.x;
    const int lane = tid & 63;
    const int wave = tid >> 6;

    if (haveInit) { ck[tid] = colKeyG[tid]; rbc[tid] = rowBestColG[tid]; }
    if (tid < N / 32) { rowAliveW[tid] = 0xFFFFFFFFu; colUsedW[tid] = 0u; }
    if (tid == 0) nA = 0;
    __syncthreads();

    for (int round = 0; round < N + 4; ++round) {
        if (round > 0 || !haveInit) {
            // ---- reset column keys ----------------------------------------
            ck[tid] = 0ULL;
            __syncthreads();

            // ---- scan alive rows ------------------------------------------
            // lane owns cols lane*16..lane*16+15 (coalesced float4 x4 per row)
            unsigned aw = (lane < N / 32) ? rowAliveW[lane] : 0u;
            unsigned um = (colUsedW[lane >> 1] >> ((lane & 1) << 4)) & 0xFFFFu;
            unsigned cHi[16]; unsigned cRow[16];
            #pragma unroll
            for (int k = 0; k < 16; ++k) { cHi[k] = 0u; cRow[k] = 0u; }

            for (int r = wave; r < N; r += 16) {
                unsigned awv = (unsigned)__builtin_amdgcn_readlane((int)aw, r >> 5);
                if (!((awv >> (r & 31)) & 1u)) continue;
                const float4* rp = (const float4*)(C + (size_t)r * N) + (lane << 2);
                float4 q0 = rp[0], q1 = rp[1], q2 = rp[2], q3 = rp[3];
                float v[16] = {q0.x, q0.y, q0.z, q0.w, q1.x, q1.y, q1.z, q1.w,
                               q2.x, q2.y, q2.z, q2.w, q3.x, q3.y, q3.z, q3.w};
                float bv = -INFINITY; int bc = 0;
                #pragma unroll
                for (int k = 0; k < 16; ++k) {
                    unsigned ou = ordf(__float_as_uint(v[k]));
                    // tie-aware (order-independent): smaller row wins on equal value
                    if (ou > cHi[k] || (ou == cHi[k] && (unsigned)r < cRow[k])) {
                        cHi[k] = ou; cRow[k] = (unsigned)r;
                    }
                    float vv = ((um >> k) & 1u) ? -INFINITY : v[k];
                    if (vv > bv) { bv = vv; bc = (lane << 4) + k; }  // k asc: min col on tie
                }
                wave_argmax(bv, bc);
                if (lane == 0) rbc[r] = (unsigned)bc;
            }
            #pragma unroll
            for (int k = 0; k < 16; ++k)
                atomicMax(&ck[(lane << 4) + k],
                          ((unsigned long long)cHi[k] << 32) |
                          (unsigned long long)(N - 1 - cRow[k]));
            __syncthreads();
        }

        // ---- match mutual-best pairs --------------------------------------
        {
            const int r = tid;
            if ((rowAliveW[r >> 5] >> (r & 31)) & 1u) {
                const int c = (int)rbc[r];
                const unsigned long long k64 = ck[c];
                const int winner = (N - 1) - (int)(unsigned)(k64 & 0xFFFFFFFFull);
                if (winner == r) {
                    out[N + r] = c;
                    atomicAnd(&rowAliveW[r >> 5], ~(1u << (r & 31)));
                    atomicOr(&colUsedW[c >> 5], 1u << (c & 31));
                    atomicAdd(&nA, 1);
                }
            }
        }
        __syncthreads();
        if (nA >= N) break;
    }

    // row-index half of the output: identity (rows sorted ascending)
    out[tid] = tid;
}

// ---------------------------------------------------------------------------
extern "C" void kernel_launch(void* const* d_in, const int* in_sizes, int n_in,
                              void* d_out, int out_size, void* d_ws, size_t ws_size,
                              hipStream_t stream) {
    const float* C = (const float*)d_in[0];
    int* out = (int*)d_out;

    if (ws_size >= (size_t)(N * 8 + N * 4)) {
        unsigned long long* colKeyG = (unsigned long long*)d_ws;
        unsigned* rowBestColG = (unsigned*)((char*)d_ws + (size_t)N * 8);
        hipMemsetAsync(d_ws, 0, (size_t)N * 8, stream);
        init_round1<<<64, 1024, 0, stream>>>(C, colKeyG, rowBestColG);
        rounds_kernel<<<1, 1024, 0, stream>>>(C, colKeyG, rowBestColG, out, 1);
    } else {
        rounds_kernel<<<1, 1024, 0, stream>>>(C, nullptr, nullptr, out, 0);
    }
}

// Round 6
// 194.472 us; speedup vs baseline: 8.1880x; 1.4975x over previous
//
#include <hip/hip_runtime.h>
#include <math.h>

#define N 1024

// (v2,f2) beats (v1,f1): larger value wins; tie -> smaller flat index
__device__ __forceinline__ bool better(float v2, int f2, float v1, int f1) {
    return (v2 > v1) || (v2 == v1 && f2 < f1);
}

// orderable uint from float bits: larger float -> larger uint (no NaN present)
__device__ __forceinline__ unsigned ordf(unsigned u) {
    return u ^ (unsigned)(((int)u >> 31) | (int)0x80000000);
}

// One reduce level via DPP (VALU latency, no DS pipe).
template<int CTRL>
__device__ __forceinline__ void dpp_step(float& v, int& f) {
    int ovi = __builtin_amdgcn_update_dpp(0, __float_as_int(v), CTRL, 0xF, 0xF, true);
    int ofi = __builtin_amdgcn_update_dpp(0, f, CTRL, 0xF, 0xF, true);
    float ov = __int_as_float(ovi);
    if (better(ov, ofi, v, f)) { v = ov; f = ofi; }
}

// Full-wave argmax on (v,f); result broadcast to all lanes.
__device__ __forceinline__ void wave_argmax(float& v, int& f) {
    dpp_step<0xB1>(v, f);    // quad_perm xor1
    dpp_step<0x4E>(v, f);    // quad_perm xor2
    dpp_step<0x141>(v, f);   // row_half_mirror (xor within 8)
    dpp_step<0x140>(v, f);   // row_mirror      (xor within 16)
    float v0 = __int_as_float(__builtin_amdgcn_readlane(__float_as_int(v), 0));
    int   f0 = __builtin_amdgcn_readlane(f, 0);
    float v1 = __int_as_float(__builtin_amdgcn_readlane(__float_as_int(v), 16));
    int   f1 = __builtin_amdgcn_readlane(f, 16);
    float v2 = __int_as_float(__builtin_amdgcn_readlane(__float_as_int(v), 32));
    int   f2 = __builtin_amdgcn_readlane(f, 32);
    float v3 = __int_as_float(__builtin_amdgcn_readlane(__float_as_int(v), 48));
    int   f3 = __builtin_amdgcn_readlane(f, 48);
    if (better(v1, f1, v0, f0)) { v0 = v1; f0 = f1; }
    if (better(v3, f3, v2, f2)) { v2 = v3; f2 = f3; }
    if (better(v2, f2, v0, f0)) { v0 = v2; f0 = f2; }
    v = v0; f = f0;
}

// ---------------------------------------------------------------------------
// Kernel 1 (grid-wide): round-1 row argmax + column keys.
// Block b owns rows [b*16, b*16+16). Column max merged via global atomicMax
// on key = (ordf(val)<<32) | (1023-row) -- order-independent, deterministic.
// ---------------------------------------------------------------------------
__global__ __launch_bounds__(1024) void init_round1(const float* __restrict__ C,
                                                    unsigned long long* __restrict__ colKeyG,
                                                    unsigned* __restrict__ rowBestColG) {
    __shared__ float rpV[16][16];
    __shared__ int   rpC[16][16];
    const int lane = threadIdx.x & 63;
    const int wave = threadIdx.x >> 6;
    const int r0 = blockIdx.x << 4;
    const int myCol = (wave << 6) + lane;

    float v[16];
    #pragma unroll
    for (int i = 0; i < 16; ++i)
        v[i] = C[(size_t)(r0 + i) * N + myCol];

    unsigned bHi = 0u; unsigned bRow = 0u;
    #pragma unroll
    for (int i = 0; i < 16; ++i) {
        unsigned ou = ordf(__float_as_uint(v[i]));
        if (ou > bHi) { bHi = ou; bRow = (unsigned)(r0 + i); }  // asc i: min row on tie
    }
    atomicMax(&colKeyG[myCol],
              ((unsigned long long)bHi << 32) | (unsigned long long)(N - 1 - bRow));

    #pragma unroll
    for (int i = 0; i < 16; ++i) {
        float bv = v[i]; int bc = myCol;
        wave_argmax(bv, bc);
        if (lane == 0) { rpV[i][wave] = bv; rpC[i][wave] = bc; }
    }
    __syncthreads();
    if (threadIdx.x < 16) {
        const int i = threadIdx.x;
        float bv = rpV[i][0]; int bc = rpC[i][0];
        #pragma unroll
        for (int w = 1; w < 16; ++w)
            if (better(rpV[i][w], rpC[i][w], bv, bc)) { bv = rpV[i][w]; bc = rpC[i][w]; }
        rowBestColG[r0 + i] = (unsigned)bc;
    }
}

// ---------------------------------------------------------------------------
// Kernel 2: parallel-greedy rounds in ONE 1024-thread workgroup.
// ck stored PERMUTED: ck[pk(c)], pk(c) = (c&15)<<6 | (c>>4), so the per-round
// atomicMax over fixed k hits consecutive u64 (4-way bank conflict, not 32).
// Alive rows kept as a compact double-buffered list, rebuilt during match.
// ---------------------------------------------------------------------------
__global__ __launch_bounds__(1024) void rounds_kernel(const float* __restrict__ C,
                                                      const unsigned long long* __restrict__ colKeyG,
                                                      const unsigned* __restrict__ rowBestColG,
                                                      int* __restrict__ out,
                                                      int haveInit) {
    __shared__ unsigned long long ck[N];          // permuted column keys
    __shared__ unsigned rbc[N];                   // row best col this round
    __shared__ unsigned short aliveList[2][N];
    __shared__ unsigned colUsedW[N / 32];
    __shared__ int cnts[2];

    const int tid = threadIdx.x;
    const int lane = tid & 63;
    const int wave = tid >> 6;

    if (haveInit) {
        ck[((tid & 15) << 6) | (tid >> 4)] = colKeyG[tid];
        rbc[tid] = rowBestColG[tid];
    }
    aliveList[0][tid] = (unsigned short)tid;
    if (tid < N / 32) colUsedW[tid] = 0u;
    if (tid == 0) { cnts[0] = N; cnts[1] = 0; }
    __syncthreads();

    int p = 0;
    for (int round = 0; round < N + 2; ++round) {
        const int cnt = cnts[p];
        if (!(round == 0 && haveInit)) {
            // ---- reset keys, zero next-round count ------------------------
            ck[tid] = 0ULL;
            if (tid == 0) cnts[p ^ 1] = 0;
            __syncthreads();                                           // B1

            // ---- scan alive rows: row-best + column-key partials ----------
            const unsigned um = (colUsedW[lane >> 1] >> ((lane & 1) << 4)) & 0xFFFFu;
            unsigned cHi[16]; unsigned cRow[16];
            #pragma unroll
            for (int k = 0; k < 16; ++k) { cHi[k] = 0u; cRow[k] = 0u; }
            bool any = false;
            for (int i = wave; i < cnt; i += 16) {
                const int r = aliveList[p][i];
                any = true;
                const float4* rp = (const float4*)(C + (size_t)r * N) + (lane << 2);
                float4 q0 = rp[0], q1 = rp[1], q2 = rp[2], q3 = rp[3];
                float v[16] = {q0.x, q0.y, q0.z, q0.w, q1.x, q1.y, q1.z, q1.w,
                               q2.x, q2.y, q2.z, q2.w, q3.x, q3.y, q3.z, q3.w};
                float bv = -INFINITY; int bc = 0;
                #pragma unroll
                for (int k = 0; k < 16; ++k) {
                    unsigned ou = ordf(__float_as_uint(v[k]));
                    // order-independent: smaller row wins on equal value
                    if (ou > cHi[k] || (ou == cHi[k] && (unsigned)r < cRow[k])) {
                        cHi[k] = ou; cRow[k] = (unsigned)r;
                    }
                    float vv = ((um >> k) & 1u) ? -INFINITY : v[k];
                    if (vv > bv) { bv = vv; bc = (lane << 4) + k; }  // k asc: min col
                }
                wave_argmax(bv, bc);
                if (lane == 0) rbc[r] = (unsigned)bc;
            }
            if (any) {
                #pragma unroll
                for (int k = 0; k < 16; ++k)
                    atomicMax(&ck[(k << 6) | lane],
                              ((unsigned long long)cHi[k] << 32) |
                              (unsigned long long)(N - 1 - cRow[k]));
            }
            __syncthreads();                                           // B2
        }

        // ---- match mutual-best pairs; rebuild alive list ------------------
        if (tid < cnt) {
            const int r = aliveList[p][tid];
            const int c = (int)rbc[r];
            const unsigned long long k64 = ck[((c & 15) << 6) | (c >> 4)];
            const int winner = (N - 1) - (int)(unsigned)(k64 & 0xFFFFFFFFull);
            if (winner == r) {
                out[N + r] = c;
                atomicOr(&colUsedW[c >> 5], 1u << (c & 31));
            } else {
                int idx = atomicAdd(&cnts[p ^ 1], 1);
                aliveList[p ^ 1][idx] = (unsigned short)r;
            }
        }
        __syncthreads();                                               // B3
        p ^= 1;
        if (cnts[p] == 0) break;
    }

    // row-index half of the output: identity (rows sorted ascending)
    out[tid] = tid;
}

// ---------------------------------------------------------------------------
extern "C" void kernel_launch(void* const* d_in, const int* in_sizes, int n_in,
                              void* d_out, int out_size, void* d_ws, size_t ws_size,
                              hipStream_t stream) {
    const float* C = (const float*)d_in[0];
    int* out = (int*)d_out;

    if (ws_size >= (size_t)(N * 8 + N * 4)) {
        unsigned long long* colKeyG = (unsigned long long*)d_ws;
        unsigned* rowBestColG = (unsigned*)((char*)d_ws + (size_t)N * 8);
        hipMemsetAsync(d_ws, 0, (size_t)N * 8, stream);
        init_round1<<<64, 1024, 0, stream>>>(C, colKeyG, rowBestColG);
        rounds_kernel<<<1, 1024, 0, stream>>>(C, colKeyG, rowBestColG, out, 1);
    } else {
        rounds_kernel<<<1, 1024, 0, stream>>>(C, nullptr, nullptr, out, 0);
    }
}